// Round 14
// baseline (2751.490 us; speedup 1.0000x reference)
//
#include <hip/hip_runtime.h>
#include <hip/hip_bf16.h>
#include <hip/hip_fp16.h>
#include <cstdint>
#include <cstddef>

// BiLSTM tagger, f32 end-to-end (fp16 Whh in LDS for the scan).
// embed -> [GEMM pre -> 8-block LSTM scan] x2 -> MLP GEMMs -> bilinear.
// Scan (r14): fp16 weights @ 4 parts/dir -> 81,600 B LDS (the size range PROVEN
// in r10/r11; r12/r13's ~160KB allocations are the suspected launch failures).
// Conflict-free chunk-major layout [25 chunks][200 rows] x 16B with lane = row
// (consecutive lanes read consecutive 16B = linear = conflict-free b128).
// 3-partner exchange at r5's proven scale: packed (tag<<32|val) u64 words in L2,
// parity slots, publish-first, guard-bounded spins. 2 barriers/step, g_lds gate
// exchange (r5 pattern). This is ALSO the disambiguating experiment for r13:
// same fp16 arithmetic at a proven LDS size -> pass = size was the bug,
// fail ~2e-2 = fp16 precision is the bug (r15 then: f32 @ 8 parts).

#define TSEQ 512
#define HDIR 200
#define INSZ 400

typedef unsigned long long u64;

// ---------------- embedding ----------------
__global__ void k_embed(const float* __restrict__ we, const float* __restrict__ pe,
                        const int* __restrict__ wi, const int* __restrict__ pi,
                        float* __restrict__ x) {
  int t = blockIdx.x;
  int w = wi[t], p = pi[t];
  const float* wrow = we + (size_t)w * 300;
  const float* prow = pe + (size_t)p * 100;
  for (int j = threadIdx.x; j < INSZ; j += blockDim.x)
    x[(size_t)t * INSZ + j] = (j < 300) ? wrow[j] : prow[j - 300];
}

__global__ void k_add(const float* __restrict__ a, const float* __restrict__ b,
                      float* __restrict__ o, int n) {
  int i = blockIdx.x * blockDim.x + threadIdx.x;
  if (i < n) o[i] = a[i] + b[i];
}

// ---------------- GEMM: C[n][m] = act(A[n][k] * B[m][k]^T + bias) ----------------
__device__ __forceinline__ void gemm_bt_body(
    const float* __restrict__ A, const float* __restrict__ B,
    const float* __restrict__ bias, float* __restrict__ C,
    int m, int k, int bias_mode, int do_relu, int bx, int by)
{
  __shared__ float As[16][68];
  __shared__ float Bs[16][68];
  const int tid = threadIdx.x;
  const int tx = tid & 15, ty = tid >> 4;
  const int row0 = by << 6, col0 = bx << 6;
  const int lr = tid >> 2;
  const int kq = (tid & 3) << 2;
  float acc[4][4] = {};

  for (int ks = 0; ks < k; ks += 16) {
    float4 a4 = *(const float4*)(A + (size_t)(row0 + lr) * k + ks + kq);
    float4 b4 = make_float4(0.f, 0.f, 0.f, 0.f);
    if (col0 + lr < m)
      b4 = *(const float4*)(B + (size_t)(col0 + lr) * k + ks + kq);
    As[kq + 0][lr] = a4.x; As[kq + 1][lr] = a4.y; As[kq + 2][lr] = a4.z; As[kq + 3][lr] = a4.w;
    Bs[kq + 0][lr] = b4.x; Bs[kq + 1][lr] = b4.y; Bs[kq + 2][lr] = b4.z; Bs[kq + 3][lr] = b4.w;
    __syncthreads();
#pragma unroll
    for (int kk = 0; kk < 16; ++kk) {
      const float4 av = *(const float4*)&As[kk][ty << 2];
      const float4 bv = *(const float4*)&Bs[kk][tx << 2];
      const float a_[4] = {av.x, av.y, av.z, av.w};
      const float b_[4] = {bv.x, bv.y, bv.z, bv.w};
#pragma unroll
      for (int i = 0; i < 4; ++i)
#pragma unroll
        for (int j = 0; j < 4; ++j)
          acc[i][j] += a_[i] * b_[j];
    }
    __syncthreads();
  }

#pragma unroll
  for (int i = 0; i < 4; ++i) {
    const int r = row0 + (ty << 2) + i;
#pragma unroll
    for (int j = 0; j < 4; ++j) {
      const int c = col0 + (tx << 2) + j;
      if (c < m) {
        float v = acc[i][j];
        if (bias_mode == 1) v += bias[c];
        else if (bias_mode == 2) v += bias[0];
        if (do_relu) v = fmaxf(v, 0.f);
        C[(size_t)r * m + c] = v;
      }
    }
  }
}

__global__ __launch_bounds__(256) void k_gemm_bt(
    const float* __restrict__ A, const float* __restrict__ B,
    const float* __restrict__ bias, float* __restrict__ C,
    int m, int k, int bias_mode, int do_relu)
{
  gemm_bt_body(A, B, bias, C, m, k, bias_mode, do_relu, blockIdx.x, blockIdx.y);
}

__global__ __launch_bounds__(256) void k_gemm_bt_dual(
    const float* __restrict__ A0, const float* __restrict__ B0,
    const float* __restrict__ bias0, float* __restrict__ C0,
    const float* __restrict__ A1, const float* __restrict__ B1,
    const float* __restrict__ bias1, float* __restrict__ C1,
    int m, int k, int bias_mode, int do_relu)
{
  const float* A = blockIdx.z ? A1 : A0;
  const float* B = blockIdx.z ? B1 : B0;
  const float* bias = blockIdx.z ? bias1 : bias0;
  float* C = blockIdx.z ? C1 : C0;
  gemm_bt_body(A, B, bias, C, m, k, bias_mode, do_relu, blockIdx.x, blockIdx.y);
}

// ---------------- LSTM scan ----------------
// Working blocks (of 32): bid&7 in {0,1}: dir = bid&7, p = bid>>3 (0..3).
// 256 threads. act = tid<200: g = tid/50, q = tid%50, local row = tid,
// global gate row = g*200 + p*50 + q. Weights fp16 chunk-major:
// uint4 at chunk*3200 + row*16 (chunk 0..24 covers cols 8c..8c+7).
// h_lds f32 [200]; g_lds f32 [200] (activated gates). Gather: tids 0..149,
// one packed word each. hbuf: u64[2 slot][2 dir][200] = (tag<<32)|bits(h).
__global__ __launch_bounds__(256)
void k_scan(const float* __restrict__ Whh,   // [2][2][800][200] f32
            const float* __restrict__ pre,   // [512][1600]
            float* __restrict__ hs,          // [512][400] (concat fwd|bwd)
            u64* hbuf,                       // zeroed by host each launch
            int layer)
{
  const int bid = blockIdx.x;
  if ((bid & 7) > 1) return;
  const int dir = bid & 7;
  const int p = bid >> 3;
  const int tid = threadIdx.x;
  const bool act = tid < 200;
  const int g = tid / 50;            // 0..3 for act (gate i,f,g,o)
  const int q = tid - g * 50;
  const int own0 = p * 50;
  const int grow = g * HDIR + own0 + q;

  extern __shared__ float smem[];
  char* w_base = (char*)smem;                  // [25][200] uint4 fp16x8 = 80,000 B
  float* h_lds = smem + 20000;                 // [200]
  float* g_lds = h_lds + HDIR;                 // [200]

  const float* WhhL = Whh + (size_t)(layer * 2 + dir) * 800 * 200;
  u64* hb_dir = hbuf + dir * HDIR;             // + slot*400

  // ---- one-time staging: coalesced f32 read -> fp16, chunk-major write ----
  for (int idx = tid; idx < 200 * 25; idx += 256) {
    const int lr = idx / 25;          // local row 0..199
    const int c8 = idx - lr * 25;     // 8-col chunk 0..24
    const int gg = lr / 50, qq = lr - gg * 50;
    const float* src = WhhL + ((size_t)(gg * HDIR + own0 + qq)) * HDIR + c8 * 8;
    const float4 v0 = *(const float4*)(src);
    const float4 v1 = *(const float4*)(src + 4);
    const __half2 p0 = __floats2half2_rn(v0.x, v0.y);
    const __half2 p1 = __floats2half2_rn(v0.z, v0.w);
    const __half2 p2 = __floats2half2_rn(v1.x, v1.y);
    const __half2 p3 = __floats2half2_rn(v1.z, v1.w);
    uint4 pk;
    pk.x = *reinterpret_cast<const unsigned*>(&p0);
    pk.y = *reinterpret_cast<const unsigned*>(&p1);
    pk.z = *reinterpret_cast<const unsigned*>(&p2);
    pk.w = *reinterpret_cast<const unsigned*>(&p3);
    *(uint4*)(w_base + c8 * 3200 + lr * 16) = pk;
  }
  for (int i = tid; i < HDIR; i += 256) h_lds[i] = 0.f;
  float c_state = 0.f;               // valid for tid < 50
  __syncthreads();

#pragma unroll 1
  for (int t = 0; t < TSEQ; ++t) {
    const int inrow = dir ? (TSEQ - 1 - t) : t;
    const int par = t & 1;

    float preval = 0.f;
    if (act)
      preval = pre[(size_t)inrow * 1600 + dir * 800 + grow];

    // gather 150 remote words (tids 0..149, 1 each); tag carries the data.
    if (t > 0 && tid < 150) {
      const int j = (tid < own0) ? tid : tid + 50;
      const u64* s = hb_dir + (size_t)par * 400 + j;
      u64 v = __hip_atomic_load(s, __ATOMIC_RELAXED, __HIP_MEMORY_SCOPE_AGENT);
      int guard = 0;
      while ((unsigned)(v >> 32) < (unsigned)t && ++guard < (1 << 18))
        v = __hip_atomic_load(s, __ATOMIC_RELAXED, __HIP_MEMORY_SCOPE_AGENT);
      union { unsigned uu; float f; } cv; cv.uu = (unsigned)v;
      h_lds[j] = cv.f;
    }
    __syncthreads();   // B1: full h_t in h_lds (own slice from prev iter)

    if (act) {
      // launder row offset: keep the 25 weight reads inside the loop (r3-r8)
      unsigned roff = (unsigned)tid * 16u;
      asm volatile("" : "+v"(roff));
      float a0 = 0.f, a1 = 0.f, a2 = 0.f, a3 = 0.f;
#pragma unroll
      for (int c = 0; c < 25; ++c) {
        const uint4 wq = *(const uint4*)(w_base + c * 3200 + roff);
        const float4 h0 = *(const float4*)(h_lds + c * 8);
        const float4 h1 = *(const float4*)(h_lds + c * 8 + 4);
        const float2 f0 = __half22float2(*reinterpret_cast<const __half2*>(&wq.x));
        const float2 f1 = __half22float2(*reinterpret_cast<const __half2*>(&wq.y));
        const float2 f2 = __half22float2(*reinterpret_cast<const __half2*>(&wq.z));
        const float2 f3 = __half22float2(*reinterpret_cast<const __half2*>(&wq.w));
        a0 += f0.x * h0.x + f2.x * h1.x;
        a1 += f0.y * h0.y + f2.y * h1.y;
        a2 += f1.x * h0.z + f3.x * h1.z;
        a3 += f1.y * h0.w + f3.y * h1.w;
      }
      const float gv = (a0 + a1) + (a2 + a3) + preval;
      const float xx = (g == 2) ? 2.f * gv : gv;     // tanh = 2*sig(2x)-1
      const float s = 1.f / (1.f + __expf(-xx));
      g_lds[tid] = (g == 2) ? (2.f * s - 1.f) : s;
    }
    __syncthreads();   // B2: g_lds ready

    if (tid < 50) {    // owner: pointwise + publish
      const float ai = g_lds[tid];
      const float af = g_lds[50 + tid];
      const float ag = g_lds[100 + tid];
      const float ao = g_lds[150 + tid];
      c_state = af * c_state + ai * ag;
      const float th = 2.f / (1.f + __expf(-2.f * c_state)) - 1.f;
      const float hv = ao * th;
      if (t != TSEQ - 1) {             // publish first: critical word leaves early
        union { float f; unsigned uu; } cv; cv.f = hv;
        const u64 pk = ((u64)(unsigned)(t + 1) << 32) | cv.uu;
        __hip_atomic_store(hb_dir + (size_t)((t + 1) & 1) * 400 + own0 + tid,
                           pk, __ATOMIC_RELAXED, __HIP_MEMORY_SCOPE_AGENT);
      }
      h_lds[own0 + tid] = hv;          // own slice for next iter (ordered by B1)
      hs[(size_t)inrow * INSZ + dir * HDIR + own0 + tid] = hv;
    }
    // no 3rd barrier: next gather writes disjoint h_lds words; B1(t+1) orders
    // the owner write before the next FMA reads.
  }
}

// ---------------- host ----------------
extern "C" void kernel_launch(void* const* d_in, const int* in_sizes, int n_in,
                              void* d_out, int out_size, void* d_ws, size_t ws_size,
                              hipStream_t stream)
{
  const float* we   = (const float*)d_in[0];
  const float* pe   = (const float*)d_in[1];
  const float* Wih  = (const float*)d_in[2];
  const float* Whh  = (const float*)d_in[3];
  const float* bih  = (const float*)d_in[4];
  const float* bhh  = (const float*)d_in[5];
  const float* W_h1 = (const float*)d_in[6];
  const float* b_h1 = (const float*)d_in[7];
  const float* W_h2 = (const float*)d_in[8];
  const float* b_h2 = (const float*)d_in[9];
  const float* W_d1 = (const float*)d_in[10];
  const float* b_d1 = (const float*)d_in[11];
  const float* W_d2 = (const float*)d_in[12];
  const float* b_d2 = (const float*)d_in[13];
  const float* W_bi = (const float*)d_in[14];
  const float* b_bi = (const float*)d_in[15];
  const int*   wi   = (const int*)d_in[16];
  const int*   pi   = (const int*)d_in[17];
  float* out = (float*)d_out;

  float* ws = (float*)d_ws;
  float* x0   = ws;                     // 512*400
  float* pre  = ws + 204800;            // 512*1600
  float* h1   = ws + 1024000;           // 512*400
  float* h2   = ws + 1228800;           // 512*400
  float* m1h  = ws + 1433600;           // 512*400
  float* m1d  = ws + 1638400;           // 512*400
  float* m2   = ws + 1843200;           // 512*400 (head)
  float* m3   = ws + 2048000;           // 512*400 (dep)
  float* t1   = ws + 2252800;           // 512*400
  float* bsum = ws + 2457600;           // 3200
  u64* hbuf0  = (u64*)(ws + 2461696);   // 800 u64, layer 0
  u64* hbuf1  = hbuf0 + 800;            // layer 1

  const int SMEM = 80000 + 2 * HDIR * 4;   // 81,600 B (proven size range, r10/r11)
  hipFuncSetAttribute((const void*)k_scan,
                      hipFuncAttributeMaxDynamicSharedMemorySize, SMEM);

  hipMemsetAsync(hbuf0, 0, 2 * 800 * sizeof(u64), stream);
  k_embed<<<TSEQ, 128, 0, stream>>>(we, pe, wi, pi, x0);
  k_add<<<(3200 + 255) / 256, 256, 0, stream>>>(bih, bhh, bsum, 3200);

  // layer 0
  k_gemm_bt<<<dim3(25, 8), 256, 0, stream>>>(x0, Wih, bsum, pre, 1600, 400, 1, 0);
  k_scan<<<32, 256, SMEM, stream>>>(Whh, pre, h1, hbuf0, 0);
  // layer 1
  k_gemm_bt<<<dim3(25, 8), 256, 0, stream>>>(h1, Wih + 1600 * 400, bsum + 1600, pre, 1600, 400, 1, 0);
  k_scan<<<32, 256, SMEM, stream>>>(Whh, pre, h2, hbuf1, 1);

  // head/dep stage 1 (dual), stage 2 (dual)
  k_gemm_bt_dual<<<dim3(7, 8, 2), 256, 0, stream>>>(h2, W_h1, b_h1, m1h,
                                                    h2, W_d1, b_d1, m1d, 400, 400, 1, 1);
  k_gemm_bt_dual<<<dim3(7, 8, 2), 256, 0, stream>>>(m1h, W_h2, b_h2, m2,
                                                    m1d, W_d2, b_d2, m3, 400, 400, 1, 1);

  // bilinear: t1[j][d] = sum_e dep[j][e] W_bi[d][e]; out[i][j] = head_i . t1_j + b
  k_gemm_bt<<<dim3(7, 8), 256, 0, stream>>>(m3, W_bi, nullptr, t1, 400, 400, 0, 0);
  k_gemm_bt<<<dim3(8, 8), 256, 0, stream>>>(m2, t1, b_bi, out, 512, 400, 2, 0);
}